// Round 7
// baseline (862.561 us; speedup 1.0000x reference)
//
#include <hip/hip_runtime.h>

#define T_TOK 8192
#define DIM   1024
#define DFF_  4096
#define NE    8
#define MAXT  144

typedef float  f32x4 __attribute__((ext_vector_type(4)));
typedef __bf16 b16x8 __attribute__((ext_vector_type(8)));
typedef unsigned short u16x4 __attribute__((ext_vector_type(4)));

__device__ __forceinline__ unsigned short f2bf(float f) {
  union { float f; unsigned int u; } v; v.f = f;
  unsigned int r = v.u + 0x7fffu + ((v.u >> 16) & 1u);
  return (unsigned short)(r >> 16);
}

__device__ __forceinline__ void gload_lds16(const void* g, void* l) {
  __builtin_amdgcn_global_load_lds((const __attribute__((address_space(1))) void*)g,
                                   (__attribute__((address_space(3))) void*)l,
                                   16, 0, 0);
}

// Counted vmcnt (T4): wait until <=N of MY wave's vmem ops outstanding; in-order
// completion => the drained ops are the oldest. Ledger is per-wave; the s_barrier
// after the wait extends the guarantee to all waves' staging loads.
#define WAITCNT(n) asm volatile("s_waitcnt vmcnt(" #n ")" ::: "memory")
// Raw barrier (no waitcnt drain) + compiler memory fences so LDS reads /
// DMA issues cannot be moved across it by the scheduler.
#define SBAR() do { asm volatile("" ::: "memory"); __builtin_amdgcn_s_barrier(); \
                    asm volatile("" ::: "memory"); } while (0)

// ---------------- transpose + fp32->bf16 convert: src [E][R][C] -> dst [E][C][R] ----------------
// float4 loads (16B/lane), ushort4 stores (8B/lane)
__global__ __launch_bounds__(256) void transpose_cvt(const float* __restrict__ src,
                                                     unsigned short* __restrict__ dst,
                                                     int R, int C) {
  __shared__ float tile[64][68];  // 68: float4-aligned rows, bank-spread on col reads
  size_t mat = (size_t)blockIdx.z * R * C;
  int c0 = blockIdx.x * 64, r0 = blockIdx.y * 64;
  int t = threadIdx.x;
  int rcol = (t & 15) * 4, rrow = t >> 4;
  const float* s = src + mat + (size_t)r0 * C + c0;
#pragma unroll
  for (int i = 0; i < 4; i++) {
    int r = rrow + i * 16;
    f32x4 v = *(const f32x4*)(s + (size_t)r * C + rcol);
    *(f32x4*)(&tile[r][rcol]) = v;
  }
  __syncthreads();
  unsigned short* d = dst + mat + (size_t)c0 * R + r0;
  int wrow4 = (t & 15) * 4, wcol = t >> 4;
#pragma unroll
  for (int i = 0; i < 4; i++) {
    int cc = wcol + i * 16;
    u16x4 o;
    o[0] = f2bf(tile[wrow4 + 0][cc]);
    o[1] = f2bf(tile[wrow4 + 1][cc]);
    o[2] = f2bf(tile[wrow4 + 2][cc]);
    o[3] = f2bf(tile[wrow4 + 3][cc]);
    *(u16x4*)(&d[(size_t)cc * R + wrow4]) = o;
  }
}

// ---------------- router: logits (fp32 exact), top-2, softmax weights, bf16 x copy,
// fused per-block expert counting ----------------
__global__ __launch_bounds__(256) void router_k(const float* __restrict__ x,
                                                const float* __restrict__ Wr,
                                                const float* __restrict__ br,
                                                unsigned short* __restrict__ Xbf,
                                                int* __restrict__ top2e,
                                                float* __restrict__ top2w,
                                                int* __restrict__ counts) {
  __shared__ int lcnt[NE];
  if (threadIdx.x < NE) lcnt[threadIdx.x] = 0;
  __syncthreads();
  int wid = threadIdx.x >> 6, lane = threadIdx.x & 63;
  int t = blockIdx.x * 4 + wid;
  const float* xr = x + (size_t)t * DIM;
  unsigned short* xb = Xbf + (size_t)t * DIM;
  float s[NE];
#pragma unroll
  for (int e = 0; e < NE; e++) s[e] = 0.f;
  for (int i = 0; i < DIM / 64; i++) {
    int dd = i * 64 + lane;
    float xv = xr[dd];
    xb[dd] = f2bf(xv);
    const float* w = Wr + (size_t)dd * NE;
#pragma unroll
    for (int e = 0; e < NE; e++) s[e] += xv * w[e];
  }
#pragma unroll
  for (int m = 32; m >= 1; m >>= 1) {
#pragma unroll
    for (int e = 0; e < NE; e++) s[e] += __shfl_xor(s[e], m, 64);
  }
  if (lane == 0) {
#pragma unroll
    for (int e = 0; e < NE; e++) s[e] += br[e];
    int e0 = 0;
#pragma unroll
    for (int e = 1; e < NE; e++) if (s[e] > s[e0]) e0 = e;
    int e1 = (e0 == 0) ? 1 : 0;
#pragma unroll
    for (int e = 0; e < NE; e++) if (e != e0 && s[e] > s[e1]) e1 = e;
    float w0 = 1.f / (1.f + expf(s[e1] - s[e0]));  // softmax over (p0,p1), p0>=p1
    top2e[2 * t] = e0; top2e[2 * t + 1] = e1;
    top2w[2 * t] = w0; top2w[2 * t + 1] = 1.f - w0;
    atomicAdd(&lcnt[e0], 1);
    atomicAdd(&lcnt[e1], 1);
  }
  __syncthreads();
  if (threadIdx.x < NE) atomicAdd(&counts[threadIdx.x], lcnt[threadIdx.x]);
}

// ---------------- scan + grouped-GEMM tile map (256-row granularity) ----------------
__global__ void scan_build(int* __restrict__ ctrl) {
  if (threadIdx.x != 0 || blockIdx.x != 0) return;
  int* counts = ctrl;          // [8]
  int* offsets = ctrl + 8;     // [8]
  int* cursors = ctrl + 16;    // [8]
  int* ntile = ctrl + 24;      // [1]
  int* tileE = ctrl + 32;          // [MAXT]
  int* tileM = ctrl + 32 + MAXT;   // [MAXT]
  int o = 0;
  for (int e = 0; e < NE; e++) { offsets[e] = o; cursors[e] = o; o += counts[e]; }
  int nt = 0;
  for (int e = 0; e < NE; e++)
    for (int m0 = 0; m0 < counts[e]; m0 += 256) { tileE[nt] = e; tileM[nt] = m0; nt++; }
  ntile[0] = nt;   // <= 71
}

// ---------------- scatter tokens into per-expert lists (block-local ranks) ----------------
__global__ __launch_bounds__(256) void scatter_k(const int* __restrict__ top2e,
                                                 const float* __restrict__ top2w,
                                                 int* __restrict__ cursors,
                                                 int* __restrict__ list_tok,
                                                 float* __restrict__ list_w) {
  __shared__ int lcnt[NE];
  __shared__ int lbase[NE];
  int tid = threadIdx.x;
  if (tid < NE) lcnt[tid] = 0;
  __syncthreads();
  int t = blockIdx.x * 256 + tid;
  int e0 = top2e[2 * t], e1 = top2e[2 * t + 1];
  int r0 = atomicAdd(&lcnt[e0], 1);
  int r1 = atomicAdd(&lcnt[e1], 1);
  __syncthreads();
  if (tid < NE) lbase[tid] = atomicAdd(&cursors[tid], lcnt[tid]);
  __syncthreads();
  int p0 = lbase[e0] + r0, p1 = lbase[e1] + r1;
  list_tok[p0] = t; list_w[p0] = top2w[2 * t];
  list_tok[p1] = t; list_w[p1] = top2w[2 * t + 1];
}

// ---------------- grouped GEMM1 + fused SwiGLU (counted-vmcnt phase schedule) ----------------
// BM=256 tokens x 128 ff-cols dual (B-panel [W1|W2] = 256x32), BK=32.
// 4-slot LDS ring (4 x 32KB = 128KB), prefetch depth 3, 8 waves 4Mx2N (wave 64x64 dual).
// Per K-tile: PH0 {issue 2 gload(kt+3), vmcnt(10), SBAR, read A+B1, 16 MFMA c1},
//             PH1 {issue 2 gload(kt+3), read B2, 16 MFMA c2, SBAR}.
// Ledger: 4 loads/wave/K-tile; at PH0 outstanding <=14, oldest 4 = tile kt -> vmcnt(10).
// Ring safety: tile kt+3 writes slot (kt+3)&3 = slot of tile kt-1, whose last read
// precedes the previous iteration's end-SBAR. Peel tail: vmcnt 8/4/0.
__global__ __launch_bounds__(512) void gemm1_k(const unsigned short* __restrict__ Xbf,
                                               const unsigned short* __restrict__ W1T,
                                               const unsigned short* __restrict__ W2T,
                                               const float* __restrict__ b1,
                                               const float* __restrict__ b2,
                                               unsigned short* __restrict__ H,
                                               const int* __restrict__ list_tok,
                                               const int* __restrict__ ctrl) {
  const int* counts = ctrl; const int* offsets = ctrl + 8;
  const int* ntile = ctrl + 24;
  const int* tileE = ctrl + 32; const int* tileM = ctrl + 32 + MAXT;
  int bt = blockIdx.y;
  if (bt >= ntile[0]) return;
  int e = tileE[bt], m0 = tileM[bt];
  int Me = counts[e], off = offsets[e];
  int n0 = blockIdx.x * 128;

  // slot layout (ushort elems): A[256][32] @0, B[256][32] @8192 (B rows 0-127 = W1 cols,
  // 128-255 = W2 cols). 16384 elems = 32KB per slot.
  __shared__ unsigned short lds[4][16384];

  int tid = threadIdx.x, lane = tid & 63, wid = tid >> 6;
  int wr = wid >> 1, wc = wid & 1;

  // staging: 32 chunks of 1KB per K-tile (chunk = 16 rows x 32 k bf16); 4 per wave.
  // LDS written linearly (chunk_base + lane*16B -> row=lane>>2, col16=lane&3);
  // global source k-col pre-swizzled with g(row)=(row>>1)&3 = (lane>>3)&3.
  const unsigned short* gsrc[4];
  unsigned ldsoff[4];
  {
    int lr = lane >> 2;
    int sc = ((lane & 3) ^ ((lane >> 3) & 3)) * 8;
#pragma unroll
    for (int j = 0; j < 4; j++) {
      int c = wid * 4 + j;
      ldsoff[j] = c * 512;
      if (c < 16) {
        int r = c * 16 + lr;
        int tok = (m0 + r < Me) ? list_tok[off + m0 + r] : list_tok[off];
        gsrc[j] = Xbf + (size_t)tok * DIM + sc;
      } else {
        int br = (c - 16) * 16 + lr;   // 0..255
        if (br < 128) gsrc[j] = W1T + ((size_t)e * DFF_ + (n0 + br)) * DIM + sc;
        else          gsrc[j] = W2T + ((size_t)e * DFF_ + (n0 + br - 128)) * DIM + sc;
      }
    }
  }

  // hoisted swizzled ds_read offsets (elements, slot-relative)
  unsigned aoff[4], b1off[4];
  {
    int colg = lane >> 4;
#pragma unroll
    for (int m = 0; m < 4; m++) {
      int row = wr * 64 + m * 16 + (lane & 15);
      aoff[m] = row * 32 + ((colg ^ ((row >> 1) & 3)) * 8);
    }
#pragma unroll
    for (int n = 0; n < 4; n++) {
      int row = wc * 64 + n * 16 + (lane & 15);
      b1off[n] = 8192 + row * 32 + ((colg ^ ((row >> 1) & 3)) * 8);
      // b2off = b1off + 128*32 (swizzle invariant under +128 rows)
    }
  }

  f32x4 acc1[4][4], acc2[4][4];
#pragma unroll
  for (int i = 0; i < 4; i++)
#pragma unroll
    for (int j = 0; j < 4; j++) {
      acc1[i][j] = f32x4{0.f, 0.f, 0.f, 0.f};
      acc2[i][j] = f32x4{0.f, 0.f, 0.f, 0.f};
    }

  b16x8 aF[4];  // persists PH0 -> PH1

  auto phase0 = [&](const unsigned short* base) {
    b16x8 bF[4];
#pragma unroll
    for (int m = 0; m < 4; m++) aF[m] = *(const b16x8*)(base + aoff[m]);
#pragma unroll
    for (int n = 0; n < 4; n++) bF[n] = *(const b16x8*)(base + b1off[n]);
    __builtin_amdgcn_s_setprio(1);
#pragma unroll
    for (int m = 0; m < 4; m++)
#pragma unroll
      for (int n = 0; n < 4; n++)
        acc1[m][n] = __builtin_amdgcn_mfma_f32_16x16x32_bf16(aF[m], bF[n], acc1[m][n], 0, 0, 0);
    __builtin_amdgcn_s_setprio(0);
  };
  auto phase1 = [&](const unsigned short* base) {
    b16x8 bF[4];
#pragma unroll
    for (int n = 0; n < 4; n++) bF[n] = *(const b16x8*)(base + b1off[n] + 128 * 32);
    __builtin_amdgcn_s_setprio(1);
#pragma unroll
    for (int m = 0; m < 4; m++)
#pragma unroll
      for (int n = 0; n < 4; n++)
        acc2[m][n] = __builtin_amdgcn_mfma_f32_16x16x32_bf16(aF[m], bF[n], acc2[m][n], 0, 0, 0);
    __builtin_amdgcn_s_setprio(0);
  };

  const int NK = DIM / 32;  // 32
  // prologue: stage tiles 0,1,2 (12 loads/wave)
#pragma unroll
  for (int tpre = 0; tpre < 3; tpre++)
#pragma unroll
    for (int j = 0; j < 4; j++)
      gload_lds16(gsrc[j] + tpre * 32, (void*)(&lds[tpre][ldsoff[j]]));

  for (int kt = 0; kt < NK - 3; kt++) {
    const unsigned short* sb = &lds[kt & 3][0];
    unsigned short* pb = &lds[(kt + 3) & 3][0];
    // PH0
    gload_lds16(gsrc[0] + (kt + 3) * 32, (void*)(pb + ldsoff[0]));
    gload_lds16(gsrc[1] + (kt + 3) * 32, (void*)(pb + ldsoff[1]));
    WAITCNT(10);
    SBAR();
    phase0(sb);
    // PH1
    gload_lds16(gsrc[2] + (kt + 3) * 32, (void*)(pb + ldsoff[2]));
    gload_lds16(gsrc[3] + (kt + 3) * 32, (void*)(pb + ldsoff[3]));
    phase1(sb);
    SBAR();
  }
  { const unsigned short* sb = &lds[(NK - 3) & 3][0];
    WAITCNT(8); SBAR(); phase0(sb); phase1(sb); }
  { const unsigned short* sb = &lds[(NK - 2) & 3][0];
    WAITCNT(4); SBAR(); phase0(sb); phase1(sb); }
  { const unsigned short* sb = &lds[(NK - 1) & 3][0];
    WAITCNT(0); SBAR(); phase0(sb); phase1(sb); }

#pragma unroll
  for (int n = 0; n < 4; n++) {
    int col = n0 + wc * 64 + n * 16 + (lane & 15);
    float bb1 = b1[e * DFF_ + col], bb2 = b2[e * DFF_ + col];
#pragma unroll
    for (int m = 0; m < 4; m++) {
      int rbase = wr * 64 + m * 16 + (lane >> 4) * 4;
#pragma unroll
      for (int r = 0; r < 4; r++) {
        int rr = rbase + r;
        if (m0 + rr < Me) {
          float c1 = acc1[m][n][r] + bb1;
          float c2 = acc2[m][n][r] + bb2;
          float h = c1 * c2 / (1.f + __expf(-c1));  // silu(c1)*c2
          H[(size_t)(off + m0 + rr) * DFF_ + col] = f2bf(h);
        }
      }
    }
  }
}

// ---------------- grouped GEMM2: y[token] += w * (H @ W3^T + b3) ----------------
// Same counted-vmcnt skeleton: BM=256 x BN=128, BK=32, 4-slot ring (4 x 24KB = 96KB),
// 3 loads/wave/K-tile -> vmcnt(9), peel 6/3/0. 1 phase x 16 MFMA per K-tile.
__global__ __launch_bounds__(512) void gemm2_k(const unsigned short* __restrict__ H,
                                               const unsigned short* __restrict__ W3T,
                                               const float* __restrict__ b3,
                                               const int* __restrict__ list_tok,
                                               const float* __restrict__ list_w,
                                               float* __restrict__ y,
                                               const int* __restrict__ ctrl) {
  const int* counts = ctrl; const int* offsets = ctrl + 8;
  const int* ntile = ctrl + 24;
  const int* tileE = ctrl + 32; const int* tileM = ctrl + 32 + MAXT;
  int bt = blockIdx.y;
  if (bt >= ntile[0]) return;
  int e = tileE[bt], m0 = tileM[bt];
  int Me = counts[e], off = offsets[e];
  int n0 = blockIdx.x * 128;

  // slot: A[256][32] @0, B[128][32] @8192 -> 12288 elems = 24KB
  __shared__ unsigned short lds[4][12288];

  int tid = threadIdx.x, lane = tid & 63, wid = tid >> 6;
  int wr = wid >> 1, wc = wid & 1;

  // staging: 24 chunks of 1KB per K-tile; 3 per wave.
  const unsigned short* gsrc[3];
  unsigned ldsoff[3];
  {
    int lr = lane >> 2;
    int sc = ((lane & 3) ^ ((lane >> 3) & 3)) * 8;
#pragma unroll
    for (int j = 0; j < 3; j++) {
      int c = wid * 3 + j;
      ldsoff[j] = c * 512;
      if (c < 16) {
        int r = c * 16 + lr;
        int pos = (m0 + r < Me) ? (off + m0 + r) : off;
        gsrc[j] = H + (size_t)pos * DFF_ + sc;
      } else {
        int br = (c - 16) * 16 + lr;   // 0..127
        gsrc[j] = W3T + ((size_t)e * DIM + (n0 + br)) * DFF_ + sc;
      }
    }
  }

  unsigned aoff[4], boff[4];
  {
    int colg = lane >> 4;
#pragma unroll
    for (int m = 0; m < 4; m++) {
      int row = wr * 64 + m * 16 + (lane & 15);
      aoff[m] = row * 32 + ((colg ^ ((row >> 1) & 3)) * 8);
    }
#pragma unroll
    for (int n = 0; n < 4; n++) {
      int row = wc * 64 + n * 16 + (lane & 15);
      boff[n] = 8192 + row * 32 + ((colg ^ ((row >> 1) & 3)) * 8);
    }
  }

  f32x4 acc[4][4];
#pragma unroll
  for (int i = 0; i < 4; i++)
#pragma unroll
    for (int j = 0; j < 4; j++) acc[i][j] = f32x4{0.f, 0.f, 0.f, 0.f};

  auto compute = [&](const unsigned short* base) {
    b16x8 aF[4], bF[4];
#pragma unroll
    for (int m = 0; m < 4; m++) aF[m] = *(const b16x8*)(base + aoff[m]);
#pragma unroll
    for (int n = 0; n < 4; n++) bF[n] = *(const b16x8*)(base + boff[n]);
    __builtin_amdgcn_s_setprio(1);
#pragma unroll
    for (int m = 0; m < 4; m++)
#pragma unroll
      for (int n = 0; n < 4; n++)
        acc[m][n] = __builtin_amdgcn_mfma_f32_16x16x32_bf16(aF[m], bF[n], acc[m][n], 0, 0, 0);
    __builtin_amdgcn_s_setprio(0);
  };

  const int NK = DFF_ / 32;  // 128
#pragma unroll
  for (int tpre = 0; tpre < 3; tpre++)
#pragma unroll
    for (int j = 0; j < 3; j++)
      gload_lds16(gsrc[j] + tpre * 32, (void*)(&lds[tpre][ldsoff[j]]));

  for (int kt = 0; kt < NK - 3; kt++) {
    const unsigned short* sb = &lds[kt & 3][0];
    unsigned short* pb = &lds[(kt + 3) & 3][0];
    gload_lds16(gsrc[0] + (kt + 3) * 32, (void*)(pb + ldsoff[0]));
    gload_lds16(gsrc[1] + (kt + 3) * 32, (void*)(pb + ldsoff[1]));
    gload_lds16(gsrc[2] + (kt + 3) * 32, (void*)(pb + ldsoff[2]));
    WAITCNT(9);
    SBAR();
    compute(sb);
    SBAR();
  }
  { WAITCNT(6); SBAR(); compute(&lds[(NK - 3) & 3][0]); }
  { WAITCNT(3); SBAR(); compute(&lds[(NK - 2) & 3][0]); }
  { WAITCNT(0); SBAR(); compute(&lds[(NK - 1) & 3][0]); }

#pragma unroll
  for (int n = 0; n < 4; n++) {
    int col = n0 + wc * 64 + n * 16 + (lane & 15);
    float bb3 = b3[e * DIM + col];
#pragma unroll
    for (int m = 0; m < 4; m++) {
      int rbase = wr * 64 + m * 16 + (lane >> 4) * 4;
#pragma unroll
      for (int r = 0; r < 4; r++) {
        int rr = rbase + r;
        if (m0 + rr < Me) {
          int pos = off + m0 + rr;
          float v = list_w[pos] * (acc[m][n][r] + bb3);
          atomicAdd(&y[(size_t)list_tok[pos] * DIM + col], v);
        }
      }
    }
  }
}

extern "C" void kernel_launch(void* const* d_in, const int* in_sizes, int n_in,
                              void* d_out, int out_size, void* d_ws, size_t ws_size,
                              hipStream_t stream) {
  (void)in_sizes; (void)n_in; (void)ws_size;
  const float* x  = (const float*)d_in[0];
  const float* Wr = (const float*)d_in[1];
  const float* br = (const float*)d_in[2];
  const float* W1 = (const float*)d_in[3];
  const float* b1 = (const float*)d_in[4];
  const float* W2 = (const float*)d_in[5];
  const float* b2 = (const float*)d_in[6];
  const float* W3 = (const float*)d_in[7];
  const float* b3 = (const float*)d_in[8];
  float* y = (float*)d_out;
  char* ws = (char*)d_ws;

  const size_t matB = (size_t)NE * DFF_ * DIM * 2;     // 64 MB per transposed bf16 matrix
  size_t oW1T = 0;
  size_t oW2T = oW1T + matB;
  size_t oXbf = oW2T + matB;                           // W3T reuses oW1T after gemm1
  size_t oH   = oXbf + (size_t)T_TOK * DIM * 2;
  size_t oT2e = oH + (size_t)2 * T_TOK * DFF_ * 2;
  size_t oT2w = oT2e + (size_t)2 * T_TOK * 4;
  size_t oLtk = oT2w + (size_t)2 * T_TOK * 4;
  size_t oLw  = oLtk + (size_t)2 * T_TOK * 4;
  size_t oCtl = oLw + (size_t)2 * T_TOK * 4;

  unsigned short* W1T = (unsigned short*)(ws + oW1T);
  unsigned short* W2T = (unsigned short*)(ws + oW2T);
  unsigned short* W3T = (unsigned short*)(ws + oW1T);  // reuse
  unsigned short* Xbf = (unsigned short*)(ws + oXbf);
  unsigned short* Hb  = (unsigned short*)(ws + oH);
  int*   top2e = (int*)(ws + oT2e);
  float* top2w = (float*)(ws + oT2w);
  int*   ltok  = (int*)(ws + oLtk);
  float* lw    = (float*)(ws + oLw);
  int*   ctrl  = (int*)(ws + oCtl);

  hipMemsetAsync(y, 0, (size_t)out_size * 4, stream);
  hipMemsetAsync(ctrl, 0, (32 + 2 * MAXT) * 4, stream);

  transpose_cvt<<<dim3(DFF_ / 64, DIM / 64, NE), 256, 0, stream>>>(W1, W1T, DIM, DFF_);
  transpose_cvt<<<dim3(DFF_ / 64, DIM / 64, NE), 256, 0, stream>>>(W2, W2T, DIM, DFF_);
  router_k<<<dim3(T_TOK / 4), 256, 0, stream>>>(x, Wr, br, Xbf, top2e, top2w, ctrl);
  scan_build<<<dim3(1), 64, 0, stream>>>(ctrl);
  scatter_k<<<dim3(T_TOK / 256), 256, 0, stream>>>(top2e, top2w, ctrl + 16, ltok, lw);
  gemm1_k<<<dim3(DFF_ / 128, 71), 512, 0, stream>>>(Xbf, W1T, W2T, b1, b2, Hb, ltok, ctrl);
  transpose_cvt<<<dim3(DIM / 64, DFF_ / 64, NE), 256, 0, stream>>>(W3, W3T, DFF_, DIM);
  gemm2_k<<<dim3(DIM / 128, 71), 512, 0, stream>>>(Hb, W3T, b3, ltok, lw, y, ctrl);
}

// Round 8
// 739.586 us; speedup vs baseline: 1.1663x; 1.1663x over previous
//
#include <hip/hip_runtime.h>

#define T_TOK 8192
#define DIM   1024
#define DFF_  4096
#define NE    8
#define MAXT  144

typedef float  f32x4 __attribute__((ext_vector_type(4)));
typedef __bf16 b16x8 __attribute__((ext_vector_type(8)));
typedef unsigned short u16x4 __attribute__((ext_vector_type(4)));

__device__ __forceinline__ unsigned short f2bf(float f) {
  union { float f; unsigned int u; } v; v.f = f;
  unsigned int r = v.u + 0x7fffu + ((v.u >> 16) & 1u);
  return (unsigned short)(r >> 16);
}

__device__ __forceinline__ void gload_lds16(const void* g, void* l) {
  __builtin_amdgcn_global_load_lds((const __attribute__((address_space(1))) void*)g,
                                   (__attribute__((address_space(3))) void*)l,
                                   16, 0, 0);
}

// Round-2 lesson: explicit vmcnt drain before barrier (replay race otherwise).
// Round-4/7 lessons: counted-vmcnt rings / coarse phase splits regress at this
// structure; stay with drain-0 2-phase and maximize MFMA per barrier instead.
#define DRAIN_VMCNT() asm volatile("s_waitcnt vmcnt(0)" ::: "memory")

// ---------------- transpose + fp32->bf16 convert: src [E][R][C] -> dst [E][C][R] ----------------
__global__ __launch_bounds__(256) void transpose_cvt(const float* __restrict__ src,
                                                     unsigned short* __restrict__ dst,
                                                     int R, int C) {
  __shared__ float tile[64][68];
  size_t mat = (size_t)blockIdx.z * R * C;
  int c0 = blockIdx.x * 64, r0 = blockIdx.y * 64;
  int t = threadIdx.x;
  int rcol = (t & 15) * 4, rrow = t >> 4;
  const float* s = src + mat + (size_t)r0 * C + c0;
#pragma unroll
  for (int i = 0; i < 4; i++) {
    int r = rrow + i * 16;
    f32x4 v = *(const f32x4*)(s + (size_t)r * C + rcol);
    *(f32x4*)(&tile[r][rcol]) = v;
  }
  __syncthreads();
  unsigned short* d = dst + mat + (size_t)c0 * R + r0;
  int wrow4 = (t & 15) * 4, wcol = t >> 4;
#pragma unroll
  for (int i = 0; i < 4; i++) {
    int cc = wcol + i * 16;
    u16x4 o;
    o[0] = f2bf(tile[wrow4 + 0][cc]);
    o[1] = f2bf(tile[wrow4 + 1][cc]);
    o[2] = f2bf(tile[wrow4 + 2][cc]);
    o[3] = f2bf(tile[wrow4 + 3][cc]);
    *(u16x4*)(&d[(size_t)cc * R + wrow4]) = o;
  }
}

// ---------------- router: logits (fp32 exact), top-2, softmax weights, bf16 x copy,
// fused per-block expert counting ----------------
__global__ __launch_bounds__(256) void router_k(const float* __restrict__ x,
                                                const float* __restrict__ Wr,
                                                const float* __restrict__ br,
                                                unsigned short* __restrict__ Xbf,
                                                int* __restrict__ top2e,
                                                float* __restrict__ top2w,
                                                int* __restrict__ counts) {
  __shared__ int lcnt[NE];
  if (threadIdx.x < NE) lcnt[threadIdx.x] = 0;
  __syncthreads();
  int wid = threadIdx.x >> 6, lane = threadIdx.x & 63;
  int t = blockIdx.x * 4 + wid;
  const float* xr = x + (size_t)t * DIM;
  unsigned short* xb = Xbf + (size_t)t * DIM;
  float s[NE];
#pragma unroll
  for (int e = 0; e < NE; e++) s[e] = 0.f;
  for (int i = 0; i < DIM / 64; i++) {
    int dd = i * 64 + lane;
    float xv = xr[dd];
    xb[dd] = f2bf(xv);
    const float* w = Wr + (size_t)dd * NE;
#pragma unroll
    for (int e = 0; e < NE; e++) s[e] += xv * w[e];
  }
#pragma unroll
  for (int m = 32; m >= 1; m >>= 1) {
#pragma unroll
    for (int e = 0; e < NE; e++) s[e] += __shfl_xor(s[e], m, 64);
  }
  if (lane == 0) {
#pragma unroll
    for (int e = 0; e < NE; e++) s[e] += br[e];
    int e0 = 0;
#pragma unroll
    for (int e = 1; e < NE; e++) if (s[e] > s[e0]) e0 = e;
    int e1 = (e0 == 0) ? 1 : 0;
#pragma unroll
    for (int e = 0; e < NE; e++) if (e != e0 && s[e] > s[e1]) e1 = e;
    float w0 = 1.f / (1.f + expf(s[e1] - s[e0]));  // softmax over (p0,p1), p0>=p1
    top2e[2 * t] = e0; top2e[2 * t + 1] = e1;
    top2w[2 * t] = w0; top2w[2 * t + 1] = 1.f - w0;
    atomicAdd(&lcnt[e0], 1);
    atomicAdd(&lcnt[e1], 1);
  }
  __syncthreads();
  if (threadIdx.x < NE) atomicAdd(&counts[threadIdx.x], lcnt[threadIdx.x]);
}

// ---------------- scan + grouped-GEMM tile maps (256-row for gemm1, 128-row for gemm2) ---------
__global__ void scan_build(int* __restrict__ ctrl) {
  if (threadIdx.x != 0 || blockIdx.x != 0) return;
  int* counts = ctrl;              // [8]
  int* offsets = ctrl + 8;         // [8]
  int* cursors = ctrl + 16;        // [8]
  int* nt256 = ctrl + 24;          // [1]
  int* nt128 = ctrl + 25;          // [1]
  int* tE256 = ctrl + 32;                 // [MAXT]
  int* tM256 = ctrl + 32 + MAXT;          // [MAXT]
  int* tE128 = ctrl + 32 + 2 * MAXT;      // [MAXT]
  int* tM128 = ctrl + 32 + 3 * MAXT;      // [MAXT]
  int o = 0;
  for (int e = 0; e < NE; e++) { offsets[e] = o; cursors[e] = o; o += counts[e]; }
  int a = 0, b = 0;
  for (int e = 0; e < NE; e++) {
    for (int m0 = 0; m0 < counts[e]; m0 += 256) { tE256[a] = e; tM256[a] = m0; a++; }
    for (int m0 = 0; m0 < counts[e]; m0 += 128) { tE128[b] = e; tM128[b] = m0; b++; }
  }
  nt256[0] = a;   // <= 71
  nt128[0] = b;   // <= 135
}

// ---------------- scatter tokens into per-expert lists (block-local ranks) ----------------
__global__ __launch_bounds__(256) void scatter_k(const int* __restrict__ top2e,
                                                 const float* __restrict__ top2w,
                                                 int* __restrict__ cursors,
                                                 int* __restrict__ list_tok,
                                                 float* __restrict__ list_w) {
  __shared__ int lcnt[NE];
  __shared__ int lbase[NE];
  int tid = threadIdx.x;
  if (tid < NE) lcnt[tid] = 0;
  __syncthreads();
  int t = blockIdx.x * 256 + tid;
  int e0 = top2e[2 * t], e1 = top2e[2 * t + 1];
  int r0 = atomicAdd(&lcnt[e0], 1);
  int r1 = atomicAdd(&lcnt[e1], 1);
  __syncthreads();
  if (tid < NE) lbase[tid] = atomicAdd(&cursors[tid], lcnt[tid]);
  __syncthreads();
  int p0 = lbase[e0] + r0, p1 = lbase[e1] + r1;
  list_tok[p0] = t; list_w[p0] = top2w[2 * t];
  list_tok[p1] = t; list_w[p1] = top2w[2 * t + 1];
}

// ---------------- grouped GEMM1 + fused SwiGLU: H = silu(X@W1+b1)*(X@W2+b2) ----------------
// 1024 threads (16 waves, 4Mx4N), BM=256 x BN=128 dual, BK=64, 2-phase drain-0 dbuf,
// 32 dual-MFMA per wave per barrier (2x r6), XOR k-swizzle g(row)=row&7 (2-way = free).
// LDS 2 x 64KB = 128KB -> 1 block/CU x 16 waves (same 16 waves/CU as the reg-capped r6,
// but half the barrier frequency per MFMA).
__global__ __launch_bounds__(1024, 4) void gemm1_k(const unsigned short* __restrict__ Xbf,
                                                   const unsigned short* __restrict__ W1T,
                                                   const unsigned short* __restrict__ W2T,
                                                   const float* __restrict__ b1,
                                                   const float* __restrict__ b2,
                                                   unsigned short* __restrict__ H,
                                                   const int* __restrict__ list_tok,
                                                   const int* __restrict__ ctrl) {
  const int* counts = ctrl; const int* offsets = ctrl + 8;
  const int* ntile = ctrl + 24;
  const int* tileE = ctrl + 32; const int* tileM = ctrl + 32 + MAXT;
  int bt = blockIdx.y;
  if (bt >= ntile[0]) return;
  int e = tileE[bt], m0 = tileM[bt];
  int Me = counts[e], off = offsets[e];
  int n0 = blockIdx.x * 128;

  // slot (ushort elems): A[256][64] @0 (16384), B1[128][64] @16384 (8192), B2 @24576 (8192)
  __shared__ unsigned short lds[2][32768];  // 2 x 64KB = 128KB

  int tid = threadIdx.x, lane = tid & 63, wid = tid >> 6;  // wid 0..15
  int wr = wid >> 2, wc = wid & 3;                         // 4M x 4N, wave = 64 x 32 dual

  // staging: 64 chunks of 1KB per K-step (chunk = 8 rows x 64 k bf16); 4 per wave.
  // LDS written linearly (row = lane>>3, col16 = lane&7); global source k-col
  // pre-swizzled with g(row) = row&7 = lane>>3.
  const unsigned short* gsrc[4];
  unsigned ldsoff[4];
  {
    int lr = lane >> 3;                            // row within chunk (0..7)
    int sc = ((lane & 7) ^ (lane >> 3)) * 8;       // swizzled k-col (elements)
#pragma unroll
    for (int j = 0; j < 4; j++) {
      int c = wid * 4 + j;                         // 0..63
      ldsoff[j] = c * 512;
      if (c < 32) {
        int r = c * 8 + lr;                        // 0..255
        int tok = (m0 + r < Me) ? list_tok[off + m0 + r] : list_tok[off];
        gsrc[j] = Xbf + (size_t)tok * DIM + sc;
      } else if (c < 48) {
        int n = n0 + (c - 32) * 8 + lr;            // 0..127 within panel
        gsrc[j] = W1T + ((size_t)e * DFF_ + n) * DIM + sc;
      } else {
        int n = n0 + (c - 48) * 8 + lr;
        gsrc[j] = W2T + ((size_t)e * DFF_ + n) * DIM + sc;
      }
    }
  }

  // hoisted swizzled ds_read offsets, per kk half (loop-invariant)
  unsigned aoff[2][4], boff[2][2];
  {
    int colg = lane >> 4;  // 0..3
#pragma unroll
    for (int kk = 0; kk < 2; kk++) {
#pragma unroll
      for (int m = 0; m < 4; m++) {
        int row = wr * 64 + m * 16 + (lane & 15);  // 0..255
        aoff[kk][m] = row * 64 + (((kk * 4 + colg) ^ (row & 7)) * 8);
      }
#pragma unroll
      for (int n = 0; n < 2; n++) {
        int row = wc * 32 + n * 16 + (lane & 15);  // 0..127
        boff[kk][n] = 16384 + row * 64 + (((kk * 4 + colg) ^ (row & 7)) * 8);
        // B2 offset = boff + 8192 (swizzle invariant under region shift)
      }
    }
  }

  f32x4 acc1[4][2], acc2[4][2];
#pragma unroll
  for (int i = 0; i < 4; i++)
#pragma unroll
    for (int j = 0; j < 2; j++) {
      acc1[i][j] = f32x4{0.f, 0.f, 0.f, 0.f};
      acc2[i][j] = f32x4{0.f, 0.f, 0.f, 0.f};
    }

  auto compute = [&](const unsigned short* base) {
#pragma unroll
    for (int kk = 0; kk < 2; kk++) {
      b16x8 aF[4], bF1[2], bF2[2];
#pragma unroll
      for (int m = 0; m < 4; m++) aF[m] = *(const b16x8*)(base + aoff[kk][m]);
#pragma unroll
      for (int n = 0; n < 2; n++) {
        bF1[n] = *(const b16x8*)(base + boff[kk][n]);
        bF2[n] = *(const b16x8*)(base + boff[kk][n] + 8192);
      }
#pragma unroll
      for (int m = 0; m < 4; m++)
#pragma unroll
        for (int n = 0; n < 2; n++) {
          acc1[m][n] = __builtin_amdgcn_mfma_f32_16x16x32_bf16(aF[m], bF1[n], acc1[m][n], 0, 0, 0);
          acc2[m][n] = __builtin_amdgcn_mfma_f32_16x16x32_bf16(aF[m], bF2[n], acc2[m][n], 0, 0, 0);
        }
    }
  };

  // prologue: stage K-step 0 into buf 0
#pragma unroll
  for (int j = 0; j < 4; j++) gload_lds16(gsrc[j], (void*)(&lds[0][ldsoff[j]]));
  DRAIN_VMCNT();
  __syncthreads();

  int cur = 0;
  const int NK = DIM / 64;  // 16
  for (int kt = 0; kt < NK; kt++) {
    if (kt + 1 < NK) {
#pragma unroll
      for (int j = 0; j < 4; j++)
        gload_lds16(gsrc[j] + (kt + 1) * 64, (void*)(&lds[cur ^ 1][ldsoff[j]]));
    }
    compute(&lds[cur][0]);
    DRAIN_VMCNT();      // this wave's prefetch DMA landed (overlapped with compute)
    __syncthreads();
    cur ^= 1;
  }

#pragma unroll
  for (int n = 0; n < 2; n++) {
    int col = n0 + wc * 32 + n * 16 + (lane & 15);
    float bb1 = b1[e * DFF_ + col], bb2 = b2[e * DFF_ + col];
#pragma unroll
    for (int m = 0; m < 4; m++) {
      int rbase = wr * 64 + m * 16 + (lane >> 4) * 4;
#pragma unroll
      for (int r = 0; r < 4; r++) {
        int rr = rbase + r;
        if (m0 + rr < Me) {
          float c1 = acc1[m][n][r] + bb1;
          float c2 = acc2[m][n][r] + bb2;
          float h = c1 * c2 / (1.f + __expf(-c1));  // silu(c1)*c2
          H[(size_t)(off + m0 + rr) * DFF_ + col] = f2bf(h);
        }
      }
    }
  }
}

// ---------------- grouped GEMM2: y[token] += w * (H @ W3^T + b3) ----------------
// Proven r6 structure: 128x128 tile, BK=64, 2-phase drain-0 dbuf, XOR k-swizzle, 64KB LDS.
__global__ __launch_bounds__(512) void gemm2_k(const unsigned short* __restrict__ H,
                                               const unsigned short* __restrict__ W3T,
                                               const float* __restrict__ b3,
                                               const int* __restrict__ list_tok,
                                               const float* __restrict__ list_w,
                                               float* __restrict__ y,
                                               const int* __restrict__ ctrl) {
  const int* counts = ctrl; const int* offsets = ctrl + 8;
  const int* ntile = ctrl + 25;                    // 128-row map
  const int* tileE = ctrl + 32 + 2 * MAXT;
  const int* tileM = ctrl + 32 + 3 * MAXT;
  int bt = blockIdx.y;
  if (bt >= ntile[0]) return;
  int e = tileE[bt], m0 = tileM[bt];
  int Me = counts[e], off = offsets[e];
  int n0 = blockIdx.x * 128;

  __shared__ unsigned short lds[2][2 * 128 * 64];  // A|B per buf, 64 KB total

  int tid = threadIdx.x, lane = tid & 63, wid = tid >> 6;
  int wr = wid >> 2, wc = wid & 3;

  const unsigned short* gsrc[4];
  unsigned ldsoff[4];
  {
    int lr = lane >> 3;                            // row within chunk (0..7)
    int sc = ((lane & 7) ^ (lane >> 3)) * 8;       // swizzled k-col, g(row)=row&7
#pragma unroll
    for (int j = 0; j < 4; j++) {
      int c = wid * 4 + j;
      ldsoff[j] = c * 512;
      if (c < 16) {
        int r = c * 8 + lr;
        int pos = (m0 + r < Me) ? (off + m0 + r) : off;
        gsrc[j] = H + (size_t)pos * DFF_ + sc;
      } else {
        int n = n0 + (c - 16) * 8 + lr;
        gsrc[j] = W3T + ((size_t)e * DIM + n) * DFF_ + sc;
      }
    }
  }

  unsigned aoff[2][4], boff[2][2];
  {
    int colg = lane >> 4;
#pragma unroll
    for (int kk = 0; kk < 2; kk++) {
#pragma unroll
      for (int fi = 0; fi < 4; fi++) {
        int row = wr * 64 + fi * 16 + (lane & 15);
        aoff[kk][fi] = row * 64 + (((kk * 4 + colg) ^ (row & 7)) * 8);
      }
#pragma unroll
      for (int fj = 0; fj < 2; fj++) {
        int row = wc * 32 + fj * 16 + (lane & 15);
        boff[kk][fj] = 128 * 64 + row * 64 + (((kk * 4 + colg) ^ (row & 7)) * 8);
      }
    }
  }

  f32x4 acc[4][2];
#pragma unroll
  for (int i = 0; i < 4; i++)
#pragma unroll
    for (int j = 0; j < 2; j++) acc[i][j] = f32x4{0.f, 0.f, 0.f, 0.f};

  auto compute = [&](const unsigned short* base) {
#pragma unroll
    for (int kk = 0; kk < 2; kk++) {
      b16x8 aF[4], bF[2];
#pragma unroll
      for (int fi = 0; fi < 4; fi++) aF[fi] = *(const b16x8*)(base + aoff[kk][fi]);
#pragma unroll
      for (int fj = 0; fj < 2; fj++) bF[fj] = *(const b16x8*)(base + boff[kk][fj]);
#pragma unroll
      for (int fi = 0; fi < 4; fi++)
#pragma unroll
        for (int fj = 0; fj < 2; fj++)
          acc[fi][fj] = __builtin_amdgcn_mfma_f32_16x16x32_bf16(aF[fi], bF[fj], acc[fi][fj], 0, 0, 0);
    }
  };

#pragma unroll
  for (int j = 0; j < 4; j++) gload_lds16(gsrc[j], (void*)(&lds[0][ldsoff[j]]));
  DRAIN_VMCNT();
  __syncthreads();

  int cur = 0;
  const int NK = DFF_ / 64;
  for (int kt = 0; kt < NK; kt++) {
    if (kt + 1 < NK) {
#pragma unroll
      for (int j = 0; j < 4; j++)
        gload_lds16(gsrc[j] + (kt + 1) * 64, (void*)(&lds[cur ^ 1][ldsoff[j]]));
    }
    compute(&lds[cur][0]);
    DRAIN_VMCNT();
    __syncthreads();
    cur ^= 1;
  }

#pragma unroll
  for (int fi = 0; fi < 4; fi++)
#pragma unroll
    for (int fj = 0; fj < 2; fj++) {
      int col = n0 + wc * 32 + fj * 16 + (lane & 15);
      float bb3 = b3[e * DIM + col];
      int rbase = wr * 64 + fi * 16 + (lane >> 4) * 4;
#pragma unroll
      for (int r = 0; r < 4; r++) {
        int rr = rbase + r;
        if (m0 + rr < Me) {
          int pos = off + m0 + rr;
          float v = list_w[pos] * (acc[fi][fj][r] + bb3);
          atomicAdd(&y[(size_t)list_tok[pos] * DIM + col], v);
        }
      }
    }
}

extern "C" void kernel_launch(void* const* d_in, const int* in_sizes, int n_in,
                              void* d_out, int out_size, void* d_ws, size_t ws_size,
                              hipStream_t stream) {
  (void)in_sizes; (void)n_in; (void)ws_size;
  const float* x  = (const float*)d_in[0];
  const float* Wr = (const float*)d_in[1];
  const float* br = (const float*)d_in[2];
  const float* W1 = (const float*)d_in[3];
  const float* b1 = (const float*)d_in[4];
  const float* W2 = (const float*)d_in[5];
  const float* b2 = (const float*)d_in[6];
  const float* W3 = (const float*)d_in[7];
  const float* b3 = (const float*)d_in[8];
  float* y = (float*)d_out;
  char* ws = (char*)d_ws;

  const size_t matB = (size_t)NE * DFF_ * DIM * 2;     // 64 MB per transposed bf16 matrix
  size_t oW1T = 0;
  size_t oW2T = oW1T + matB;
  size_t oXbf = oW2T + matB;                           // W3T reuses oW1T after gemm1
  size_t oH   = oXbf + (size_t)T_TOK * DIM * 2;
  size_t oT2e = oH + (size_t)2 * T_TOK * DFF_ * 2;
  size_t oT2w = oT2e + (size_t)2 * T_TOK * 4;
  size_t oLtk = oT2w + (size_t)2 * T_TOK * 4;
  size_t oLw  = oLtk + (size_t)2 * T_TOK * 4;
  size_t oCtl = oLw + (size_t)2 * T_TOK * 4;

  unsigned short* W1T = (unsigned short*)(ws + oW1T);
  unsigned short* W2T = (unsigned short*)(ws + oW2T);
  unsigned short* W3T = (unsigned short*)(ws + oW1T);  // reuse
  unsigned short* Xbf = (unsigned short*)(ws + oXbf);
  unsigned short* Hb  = (unsigned short*)(ws + oH);
  int*   top2e = (int*)(ws + oT2e);
  float* top2w = (float*)(ws + oT2w);
  int*   ltok  = (int*)(ws + oLtk);
  float* lw    = (float*)(ws + oLw);
  int*   ctrl  = (int*)(ws + oCtl);

  hipMemsetAsync(y, 0, (size_t)out_size * 4, stream);
  hipMemsetAsync(ctrl, 0, (32 + 4 * MAXT) * 4, stream);

  transpose_cvt<<<dim3(DFF_ / 64, DIM / 64, NE), 256, 0, stream>>>(W1, W1T, DIM, DFF_);
  transpose_cvt<<<dim3(DFF_ / 64, DIM / 64, NE), 256, 0, stream>>>(W2, W2T, DIM, DFF_);
  router_k<<<dim3(T_TOK / 4), 256, 0, stream>>>(x, Wr, br, Xbf, top2e, top2w, ctrl);
  scan_build<<<dim3(1), 64, 0, stream>>>(ctrl);
  scatter_k<<<dim3(T_TOK / 256), 256, 0, stream>>>(top2e, top2w, ctrl + 16, ltok, lw);
  gemm1_k<<<dim3(DFF_ / 128, 71), 1024, 0, stream>>>(Xbf, W1T, W2T, b1, b2, Hb, ltok, ctrl);
  transpose_cvt<<<dim3(DIM / 64, DFF_ / 64, NE), 256, 0, stream>>>(W3, W3T, DFF_, DIM);
  gemm2_k<<<dim3(DIM / 128, MAXT - 8), 512, 0, stream>>>(Hb, W3T, b3, ltok, lw, y, ctrl);
}

// Round 9
// 706.678 us; speedup vs baseline: 1.2206x; 1.0466x over previous
//
#include <hip/hip_runtime.h>

#define T_TOK 8192
#define DIM   1024
#define DFF_  4096
#define NE    8
#define MAXT  144

typedef float  f32x4 __attribute__((ext_vector_type(4)));
typedef __bf16 b16x8 __attribute__((ext_vector_type(8)));
typedef unsigned short u16x4 __attribute__((ext_vector_type(4)));

__device__ __forceinline__ unsigned short f2bf(float f) {
  union { float f; unsigned int u; } v; v.f = f;
  unsigned int r = v.u + 0x7fffu + ((v.u >> 16) & 1u);
  return (unsigned short)(r >> 16);
}

__device__ __forceinline__ void gload_lds16(const void* g, void* l) {
  __builtin_amdgcn_global_load_lds((const __attribute__((address_space(1))) void*)g,
                                   (__attribute__((address_space(3))) void*)l,
                                   16, 0, 0);
}

// Round-2 lesson: explicit vmcnt drain before barrier (replay race otherwise).
// Round-4/7 lessons: counted-vmcnt rings / coarse phase splits regress here.
// Round-8 lesson (confirmed): at fixed 16 waves/CU, wins come from more MFMA
// per drain-barrier: 1024-thr / BK=64 / 32 MFMA/wave/barrier geometry.
#define DRAIN_VMCNT() asm volatile("s_waitcnt vmcnt(0)" ::: "memory")

// ---------------- transpose + fp32->bf16 convert: src [E][R][C] -> dst [E][C][R] ----------------
__global__ __launch_bounds__(256) void transpose_cvt(const float* __restrict__ src,
                                                     unsigned short* __restrict__ dst,
                                                     int R, int C) {
  __shared__ float tile[64][68];
  size_t mat = (size_t)blockIdx.z * R * C;
  int c0 = blockIdx.x * 64, r0 = blockIdx.y * 64;
  int t = threadIdx.x;
  int rcol = (t & 15) * 4, rrow = t >> 4;
  const float* s = src + mat + (size_t)r0 * C + c0;
#pragma unroll
  for (int i = 0; i < 4; i++) {
    int r = rrow + i * 16;
    f32x4 v = *(const f32x4*)(s + (size_t)r * C + rcol);
    *(f32x4*)(&tile[r][rcol]) = v;
  }
  __syncthreads();
  unsigned short* d = dst + mat + (size_t)c0 * R + r0;
  int wrow4 = (t & 15) * 4, wcol = t >> 4;
#pragma unroll
  for (int i = 0; i < 4; i++) {
    int cc = wcol + i * 16;
    u16x4 o;
    o[0] = f2bf(tile[wrow4 + 0][cc]);
    o[1] = f2bf(tile[wrow4 + 1][cc]);
    o[2] = f2bf(tile[wrow4 + 2][cc]);
    o[3] = f2bf(tile[wrow4 + 3][cc]);
    *(u16x4*)(&d[(size_t)cc * R + wrow4]) = o;
  }
}

// ---------------- router: logits (fp32 exact), top-2, softmax weights, bf16 x copy,
// fused per-block expert counting ----------------
__global__ __launch_bounds__(256) void router_k(const float* __restrict__ x,
                                                const float* __restrict__ Wr,
                                                const float* __restrict__ br,
                                                unsigned short* __restrict__ Xbf,
                                                int* __restrict__ top2e,
                                                float* __restrict__ top2w,
                                                int* __restrict__ counts) {
  __shared__ int lcnt[NE];
  if (threadIdx.x < NE) lcnt[threadIdx.x] = 0;
  __syncthreads();
  int wid = threadIdx.x >> 6, lane = threadIdx.x & 63;
  int t = blockIdx.x * 4 + wid;
  const float* xr = x + (size_t)t * DIM;
  unsigned short* xb = Xbf + (size_t)t * DIM;
  float s[NE];
#pragma unroll
  for (int e = 0; e < NE; e++) s[e] = 0.f;
  for (int i = 0; i < DIM / 64; i++) {
    int dd = i * 64 + lane;
    float xv = xr[dd];
    xb[dd] = f2bf(xv);
    const float* w = Wr + (size_t)dd * NE;
#pragma unroll
    for (int e = 0; e < NE; e++) s[e] += xv * w[e];
  }
#pragma unroll
  for (int m = 32; m >= 1; m >>= 1) {
#pragma unroll
    for (int e = 0; e < NE; e++) s[e] += __shfl_xor(s[e], m, 64);
  }
  if (lane == 0) {
#pragma unroll
    for (int e = 0; e < NE; e++) s[e] += br[e];
    int e0 = 0;
#pragma unroll
    for (int e = 1; e < NE; e++) if (s[e] > s[e0]) e0 = e;
    int e1 = (e0 == 0) ? 1 : 0;
#pragma unroll
    for (int e = 0; e < NE; e++) if (e != e0 && s[e] > s[e1]) e1 = e;
    float w0 = 1.f / (1.f + expf(s[e1] - s[e0]));  // softmax over (p0,p1), p0>=p1
    top2e[2 * t] = e0; top2e[2 * t + 1] = e1;
    top2w[2 * t] = w0; top2w[2 * t + 1] = 1.f - w0;
    atomicAdd(&lcnt[e0], 1);
    atomicAdd(&lcnt[e1], 1);
  }
  __syncthreads();
  if (threadIdx.x < NE) atomicAdd(&counts[threadIdx.x], lcnt[threadIdx.x]);
}

// ---------------- scan + grouped-GEMM tile map (256-row granularity) ----------------
__global__ void scan_build(int* __restrict__ ctrl) {
  if (threadIdx.x != 0 || blockIdx.x != 0) return;
  int* counts = ctrl;              // [8]
  int* offsets = ctrl + 8;         // [8]
  int* cursors = ctrl + 16;        // [8]
  int* nt256 = ctrl + 24;          // [1]
  int* tE256 = ctrl + 32;                 // [MAXT]
  int* tM256 = ctrl + 32 + MAXT;          // [MAXT]
  int o = 0;
  for (int e = 0; e < NE; e++) { offsets[e] = o; cursors[e] = o; o += counts[e]; }
  int a = 0;
  for (int e = 0; e < NE; e++)
    for (int m0 = 0; m0 < counts[e]; m0 += 256) { tE256[a] = e; tM256[a] = m0; a++; }
  nt256[0] = a;   // <= 71
}

// ---------------- scatter tokens into per-expert lists (block-local ranks) ----------------
__global__ __launch_bounds__(256) void scatter_k(const int* __restrict__ top2e,
                                                 const float* __restrict__ top2w,
                                                 int* __restrict__ cursors,
                                                 int* __restrict__ list_tok,
                                                 float* __restrict__ list_w) {
  __shared__ int lcnt[NE];
  __shared__ int lbase[NE];
  int tid = threadIdx.x;
  if (tid < NE) lcnt[tid] = 0;
  __syncthreads();
  int t = blockIdx.x * 256 + tid;
  int e0 = top2e[2 * t], e1 = top2e[2 * t + 1];
  int r0 = atomicAdd(&lcnt[e0], 1);
  int r1 = atomicAdd(&lcnt[e1], 1);
  __syncthreads();
  if (tid < NE) lbase[tid] = atomicAdd(&cursors[tid], lcnt[tid]);
  __syncthreads();
  int p0 = lbase[e0] + r0, p1 = lbase[e1] + r1;
  list_tok[p0] = t; list_w[p0] = top2w[2 * t];
  list_tok[p1] = t; list_w[p1] = top2w[2 * t + 1];
}

// ---------------- grouped GEMM1 + fused SwiGLU: H = silu(X@W1+b1)*(X@W2+b2) ----------------
// (r8 proven) 1024 threads (16 waves, 4Mx4N), BM=256 x BN=128 dual, BK=64, 2-phase
// drain-0 dbuf, 32 dual-MFMA per wave per barrier, XOR k-swizzle g(row)=row&7.
__global__ __launch_bounds__(1024, 4) void gemm1_k(const unsigned short* __restrict__ Xbf,
                                                   const unsigned short* __restrict__ W1T,
                                                   const unsigned short* __restrict__ W2T,
                                                   const float* __restrict__ b1,
                                                   const float* __restrict__ b2,
                                                   unsigned short* __restrict__ H,
                                                   const int* __restrict__ list_tok,
                                                   const int* __restrict__ ctrl) {
  const int* counts = ctrl; const int* offsets = ctrl + 8;
  const int* ntile = ctrl + 24;
  const int* tileE = ctrl + 32; const int* tileM = ctrl + 32 + MAXT;
  int bt = blockIdx.y;
  if (bt >= ntile[0]) return;
  int e = tileE[bt], m0 = tileM[bt];
  int Me = counts[e], off = offsets[e];
  int n0 = blockIdx.x * 128;

  // slot (ushort elems): A[256][64] @0 (16384), B1[128][64] @16384 (8192), B2 @24576 (8192)
  __shared__ unsigned short lds[2][32768];  // 2 x 64KB = 128KB

  int tid = threadIdx.x, lane = tid & 63, wid = tid >> 6;  // wid 0..15
  int wr = wid >> 2, wc = wid & 3;                         // 4M x 4N, wave = 64 x 32 dual

  const unsigned short* gsrc[4];
  unsigned ldsoff[4];
  {
    int lr = lane >> 3;                            // row within chunk (0..7)
    int sc = ((lane & 7) ^ (lane >> 3)) * 8;       // swizzled k-col (elements)
#pragma unroll
    for (int j = 0; j < 4; j++) {
      int c = wid * 4 + j;                         // 0..63
      ldsoff[j] = c * 512;
      if (c < 32) {
        int r = c * 8 + lr;                        // 0..255
        int tok = (m0 + r < Me) ? list_tok[off + m0 + r] : list_tok[off];
        gsrc[j] = Xbf + (size_t)tok * DIM + sc;
      } else if (c < 48) {
        int n = n0 + (c - 32) * 8 + lr;            // 0..127 within panel
        gsrc[j] = W1T + ((size_t)e * DFF_ + n) * DIM + sc;
      } else {
        int n = n0 + (c - 48) * 8 + lr;
        gsrc[j] = W2T + ((size_t)e * DFF_ + n) * DIM + sc;
      }
    }
  }

  unsigned aoff[2][4], boff[2][2];
  {
    int colg = lane >> 4;  // 0..3
#pragma unroll
    for (int kk = 0; kk < 2; kk++) {
#pragma unroll
      for (int m = 0; m < 4; m++) {
        int row = wr * 64 + m * 16 + (lane & 15);  // 0..255
        aoff[kk][m] = row * 64 + (((kk * 4 + colg) ^ (row & 7)) * 8);
      }
#pragma unroll
      for (int n = 0; n < 2; n++) {
        int row = wc * 32 + n * 16 + (lane & 15);  // 0..127
        boff[kk][n] = 16384 + row * 64 + (((kk * 4 + colg) ^ (row & 7)) * 8);
      }
    }
  }

  f32x4 acc1[4][2], acc2[4][2];
#pragma unroll
  for (int i = 0; i < 4; i++)
#pragma unroll
    for (int j = 0; j < 2; j++) {
      acc1[i][j] = f32x4{0.f, 0.f, 0.f, 0.f};
      acc2[i][j] = f32x4{0.f, 0.f, 0.f, 0.f};
    }

  auto compute = [&](const unsigned short* base) {
#pragma unroll
    for (int kk = 0; kk < 2; kk++) {
      b16x8 aF[4], bF1[2], bF2[2];
#pragma unroll
      for (int m = 0; m < 4; m++) aF[m] = *(const b16x8*)(base + aoff[kk][m]);
#pragma unroll
      for (int n = 0; n < 2; n++) {
        bF1[n] = *(const b16x8*)(base + boff[kk][n]);
        bF2[n] = *(const b16x8*)(base + boff[kk][n] + 8192);
      }
#pragma unroll
      for (int m = 0; m < 4; m++)
#pragma unroll
        for (int n = 0; n < 2; n++) {
          acc1[m][n] = __builtin_amdgcn_mfma_f32_16x16x32_bf16(aF[m], bF1[n], acc1[m][n], 0, 0, 0);
          acc2[m][n] = __builtin_amdgcn_mfma_f32_16x16x32_bf16(aF[m], bF2[n], acc2[m][n], 0, 0, 0);
        }
    }
  };

#pragma unroll
  for (int j = 0; j < 4; j++) gload_lds16(gsrc[j], (void*)(&lds[0][ldsoff[j]]));
  DRAIN_VMCNT();
  __syncthreads();

  int cur = 0;
  const int NK = DIM / 64;  // 16
  for (int kt = 0; kt < NK; kt++) {
    if (kt + 1 < NK) {
#pragma unroll
      for (int j = 0; j < 4; j++)
        gload_lds16(gsrc[j] + (kt + 1) * 64, (void*)(&lds[cur ^ 1][ldsoff[j]]));
    }
    compute(&lds[cur][0]);
    DRAIN_VMCNT();
    __syncthreads();
    cur ^= 1;
  }

#pragma unroll
  for (int n = 0; n < 2; n++) {
    int col = n0 + wc * 32 + n * 16 + (lane & 15);
    float bb1 = b1[e * DFF_ + col], bb2 = b2[e * DFF_ + col];
#pragma unroll
    for (int m = 0; m < 4; m++) {
      int rbase = wr * 64 + m * 16 + (lane >> 4) * 4;
#pragma unroll
      for (int r = 0; r < 4; r++) {
        int rr = rbase + r;
        if (m0 + rr < Me) {
          float c1 = acc1[m][n][r] + bb1;
          float c2 = acc2[m][n][r] + bb2;
          float h = c1 * c2 / (1.f + __expf(-c1));  // silu(c1)*c2
          H[(size_t)(off + m0 + rr) * DFF_ + col] = f2bf(h);
        }
      }
    }
  }
}

// ---------------- grouped GEMM2: y[token] += w * (H @ W3^T + b3) ----------------
// r8-gemm1 geometry applied: 1024 threads (16 waves, 4Mx4N), BM=256 x BN=256, BK=64,
// 2-phase drain-0 dbuf, wave tile 64x64, 32 MFMA/wave/barrier, XOR k-swizzle,
// LDS 2 x 64KB = 128KB. BN=256 also halves H re-reads (grid-x 4 instead of 8).
__global__ __launch_bounds__(1024, 4) void gemm2_k(const unsigned short* __restrict__ H,
                                                   const unsigned short* __restrict__ W3T,
                                                   const float* __restrict__ b3,
                                                   const int* __restrict__ list_tok,
                                                   const float* __restrict__ list_w,
                                                   float* __restrict__ y,
                                                   const int* __restrict__ ctrl) {
  const int* counts = ctrl; const int* offsets = ctrl + 8;
  const int* ntile = ctrl + 24;
  const int* tileE = ctrl + 32; const int* tileM = ctrl + 32 + MAXT;
  int bt = blockIdx.y;
  if (bt >= ntile[0]) return;
  int e = tileE[bt], m0 = tileM[bt];
  int Me = counts[e], off = offsets[e];
  int n0 = blockIdx.x * 256;

  // slot (ushort elems): A[256][64] @0 (16384), B[256][64] @16384 (16384)
  __shared__ unsigned short lds[2][32768];  // 2 x 64KB = 128KB

  int tid = threadIdx.x, lane = tid & 63, wid = tid >> 6;  // wid 0..15
  int wr = wid >> 2, wc = wid & 3;                         // 4M x 4N, wave = 64 x 64

  const unsigned short* gsrc[4];
  unsigned ldsoff[4];
  {
    int lr = lane >> 3;                            // row within chunk (0..7)
    int sc = ((lane & 7) ^ (lane >> 3)) * 8;       // swizzled k-col, g(row)=row&7
#pragma unroll
    for (int j = 0; j < 4; j++) {
      int c = wid * 4 + j;                         // 0..63
      ldsoff[j] = c * 512;
      if (c < 32) {
        int r = c * 8 + lr;                        // 0..255
        int pos = (m0 + r < Me) ? (off + m0 + r) : off;
        gsrc[j] = H + (size_t)pos * DFF_ + sc;
      } else {
        int n = n0 + (c - 32) * 8 + lr;            // 0..255 within panel
        gsrc[j] = W3T + ((size_t)e * DIM + n) * DFF_ + sc;
      }
    }
  }

  unsigned aoff[2][4], boff[2][4];
  {
    int colg = lane >> 4;
#pragma unroll
    for (int kk = 0; kk < 2; kk++) {
#pragma unroll
      for (int m = 0; m < 4; m++) {
        int row = wr * 64 + m * 16 + (lane & 15);  // 0..255
        aoff[kk][m] = row * 64 + (((kk * 4 + colg) ^ (row & 7)) * 8);
      }
#pragma unroll
      for (int n = 0; n < 4; n++) {
        int row = wc * 64 + n * 16 + (lane & 15);  // 0..255
        boff[kk][n] = 16384 + row * 64 + (((kk * 4 + colg) ^ (row & 7)) * 8);
      }
    }
  }

  f32x4 acc[4][4];
#pragma unroll
  for (int i = 0; i < 4; i++)
#pragma unroll
    for (int j = 0; j < 4; j++) acc[i][j] = f32x4{0.f, 0.f, 0.f, 0.f};

  auto compute = [&](const unsigned short* base) {
#pragma unroll
    for (int kk = 0; kk < 2; kk++) {
      b16x8 aF[4], bF[4];
#pragma unroll
      for (int m = 0; m < 4; m++) aF[m] = *(const b16x8*)(base + aoff[kk][m]);
#pragma unroll
      for (int n = 0; n < 4; n++) bF[n] = *(const b16x8*)(base + boff[kk][n]);
#pragma unroll
      for (int m = 0; m < 4; m++)
#pragma unroll
        for (int n = 0; n < 4; n++)
          acc[m][n] = __builtin_amdgcn_mfma_f32_16x16x32_bf16(aF[m], bF[n], acc[m][n], 0, 0, 0);
    }
  };

#pragma unroll
  for (int j = 0; j < 4; j++) gload_lds16(gsrc[j], (void*)(&lds[0][ldsoff[j]]));
  DRAIN_VMCNT();
  __syncthreads();

  int cur = 0;
  const int NK = DFF_ / 64;  // 64
  for (int kt = 0; kt < NK; kt++) {
    if (kt + 1 < NK) {
#pragma unroll
      for (int j = 0; j < 4; j++)
        gload_lds16(gsrc[j] + (kt + 1) * 64, (void*)(&lds[cur ^ 1][ldsoff[j]]));
    }
    compute(&lds[cur][0]);
    DRAIN_VMCNT();
    __syncthreads();
    cur ^= 1;
  }

#pragma unroll
  for (int n = 0; n < 4; n++) {
    int col = n0 + wc * 64 + n * 16 + (lane & 15);
    float bb3 = b3[e * DIM + col];
#pragma unroll
    for (int m = 0; m < 4; m++) {
      int rbase = wr * 64 + m * 16 + (lane >> 4) * 4;
#pragma unroll
      for (int r = 0; r < 4; r++) {
        int rr = rbase + r;
        if (m0 + rr < Me) {
          int pos = off + m0 + rr;
          float v = list_w[pos] * (acc[m][n][r] + bb3);
          atomicAdd(&y[(size_t)list_tok[pos] * DIM + col], v);
        }
      }
    }
  }
}

extern "C" void kernel_launch(void* const* d_in, const int* in_sizes, int n_in,
                              void* d_out, int out_size, void* d_ws, size_t ws_size,
                              hipStream_t stream) {
  (void)in_sizes; (void)n_in; (void)ws_size;
  const float* x  = (const float*)d_in[0];
  const float* Wr = (const float*)d_in[1];
  const float* br = (const float*)d_in[2];
  const float* W1 = (const float*)d_in[3];
  const float* b1 = (const float*)d_in[4];
  const float* W2 = (const float*)d_in[5];
  const float* b2 = (const float*)d_in[6];
  const float* W3 = (const float*)d_in[7];
  const float* b3 = (const float*)d_in[8];
  float* y = (float*)d_out;
  char* ws = (char*)d_ws;

  const size_t matB = (size_t)NE * DFF_ * DIM * 2;     // 64 MB per transposed bf16 matrix
  size_t oW1T = 0;
  size_t oW2T = oW1T + matB;
  size_t oXbf = oW2T + matB;                           // W3T reuses oW1T after gemm1
  size_t oH   = oXbf + (size_t)T_TOK * DIM * 2;
  size_t oT2e = oH + (size_t)2 * T_TOK * DFF_ * 2;
  size_t oT2w = oT2e + (size_t)2 * T_TOK * 4;
  size_t oLtk = oT2w + (size_t)2 * T_TOK * 4;
  size_t oLw  = oLtk + (size_t)2 * T_TOK * 4;
  size_t oCtl = oLw + (size_t)2 * T_TOK * 4;

  unsigned short* W1T = (unsigned short*)(ws + oW1T);
  unsigned short* W2T = (unsigned short*)(ws + oW2T);
  unsigned short* W3T = (unsigned short*)(ws + oW1T);  // reuse
  unsigned short* Xbf = (unsigned short*)(ws + oXbf);
  unsigned short* Hb  = (unsigned short*)(ws + oH);
  int*   top2e = (int*)(ws + oT2e);
  float* top2w = (float*)(ws + oT2w);
  int*   ltok  = (int*)(ws + oLtk);
  float* lw    = (float*)(ws + oLw);
  int*   ctrl  = (int*)(ws + oCtl);

  hipMemsetAsync(y, 0, (size_t)out_size * 4, stream);
  hipMemsetAsync(ctrl, 0, (32 + 2 * MAXT) * 4, stream);

  transpose_cvt<<<dim3(DFF_ / 64, DIM / 64, NE), 256, 0, stream>>>(W1, W1T, DIM, DFF_);
  transpose_cvt<<<dim3(DFF_ / 64, DIM / 64, NE), 256, 0, stream>>>(W2, W2T, DIM, DFF_);
  router_k<<<dim3(T_TOK / 4), 256, 0, stream>>>(x, Wr, br, Xbf, top2e, top2w, ctrl);
  scan_build<<<dim3(1), 64, 0, stream>>>(ctrl);
  scatter_k<<<dim3(T_TOK / 256), 256, 0, stream>>>(top2e, top2w, ctrl + 16, ltok, lw);
  gemm1_k<<<dim3(DFF_ / 128, 71), 1024, 0, stream>>>(Xbf, W1T, W2T, b1, b2, Hb, ltok, ctrl);
  transpose_cvt<<<dim3(DIM / 64, DFF_ / 64, NE), 256, 0, stream>>>(W3, W3T, DFF_, DIM);
  gemm2_k<<<dim3(DIM / 256, 71), 1024, 0, stream>>>(Hb, W3T, b3, ltok, lw, y, ctrl);
}